// Round 3
// baseline (707.756 us; speedup 1.0000x reference)
//
#include <hip/hip_runtime.h>

#define L 2048
#define CIN 16
#define GROUPS 4
#define NEG_INF  -1000000000.0f
#define POS_THRESH -100000000.0f

// ---------------------------------------------------------------------------
// Kernel A: sparsemax tau, one wave per row, FIXED-COST exact algorithm.
// (unchanged from round 2 — isolate conv changes)
// ---------------------------------------------------------------------------
__global__ __launch_bounds__(256) void tau_kernel(const float* __restrict__ scores,
                                                  float* __restrict__ tau_out) {
    const int wid  = (blockIdx.x << 2) + (threadIdx.x >> 6);
    const int lane = threadIdx.x & 63;
    const int ws   = threadIdx.x >> 6;            // wave slot in block
    const int ch   = wid >> 11;
    const int row  = wid & 2047;
    const int n    = row + 1;
    const float* zrow = scores + ((size_t)ch * L + row) * L;

    float v[32];
    float m = NEG_INF;
#pragma unroll
    for (int j = 0; j < 8; ++j) {
        int c4 = lane + (j << 6);
        int c  = c4 << 2;
        float4 z = make_float4(NEG_INF, NEG_INF, NEG_INF, NEG_INF);
        if (c < n) z = *((const float4*)zrow + c4);
        v[4*j+0] = (c + 0 < n) ? z.x : NEG_INF;
        v[4*j+1] = (c + 1 < n) ? z.y : NEG_INF;
        v[4*j+2] = (c + 2 < n) ? z.z : NEG_INF;
        v[4*j+3] = (c + 3 < n) ? z.w : NEG_INF;
        m = fmaxf(m, fmaxf(fmaxf(v[4*j+0], v[4*j+1]), fmaxf(v[4*j+2], v[4*j+3])));
    }
#pragma unroll
    for (int d = 32; d; d >>= 1) m = fmaxf(m, __shfl_xor(m, d, 64));

    const float thr = m - 1.0f;

    // ---- compact candidates {v > thr} into per-wave LDS buffer ----
    __shared__ float buf[4][64];
    int base = 0;
#pragma unroll
    for (int j = 0; j < 32; ++j) {
        bool p = v[j] > thr;
        unsigned long long mask = __ballot(p);
        if (mask) {
            if (p) {
                int pos = __builtin_amdgcn_mbcnt_lo((unsigned)mask, 0);
                pos = __builtin_amdgcn_mbcnt_hi((unsigned)(mask >> 32), pos);
                pos += base;
                if (pos < 64) buf[ws][pos] = v[j];
            }
            base += __popcll(mask);
        }
    }
    __syncthreads();
    const int cnt = base;

    float tau;
    if (cnt <= 64) {
        float x = (lane < cnt) ? buf[ws][lane] : NEG_INF;
        // bitonic sort, descending across 64 lanes
#pragma unroll
        for (int k = 2; k <= 64; k <<= 1) {
#pragma unroll
            for (int j = k >> 1; j > 0; j >>= 1) {
                float p = __shfl_xor(x, j, 64);
                bool desc    = ((lane & k) == 0);
                bool earlier = ((lane & j) == 0);
                float mx = fmaxf(x, p), mn = fminf(x, p);
                x = (desc == earlier) ? mx : mn;
            }
        }
        // inclusive prefix sum
        float csum = x;
#pragma unroll
        for (int d = 1; d < 64; d <<= 1) {
            float y = __shfl_up(csum, d, 64);
            if (lane >= d) csum += y;
        }
        bool cond = (1.0f + (float)(lane + 1) * x > csum) && (x > POS_THRESH);
        unsigned long long cmask = __ballot(cond);
        int k = (int)__popcll(cmask);             // k >= 1 always (max elem qualifies)
        float ck = __shfl(csum, k - 1, 64);
        tau = (ck - 1.0f) / (float)k;
    } else {
        // Michelot fallback — correctness safety net only.
        tau = thr;
        int k_prev = -1;
        for (int it = 0; it < 64; ++it) {
            float S = 0.0f, Kf = 0.0f;
#pragma unroll
            for (int j = 0; j < 32; ++j)
                if (v[j] > tau) { S += v[j]; Kf += 1.0f; }
#pragma unroll
            for (int d = 32; d; d >>= 1) {
                S  += __shfl_xor(S,  d, 64);
                Kf += __shfl_xor(Kf, d, 64);
            }
            int K = (int)Kf;
            if (K == k_prev) break;
            tau = (S - 1.0f) / Kf;
            k_prev = K;
        }
    }
    if (lane == 0) tau_out[ch * L + row] = tau;
}

// ---------------------------------------------------------------------------
// Kernel B: grouped 3x3 conv over on-the-fly probs = max(score - tau, 0).
// Tile 16 rows x 64 cols x 4 oc. Block 256 thr = 4 waves; wave = oc;
// lane = (rq = lane>>4, col4 = lane&15) -> 4 cols x 4 rows of output.
//
// LDS layout (per ic buffer of 1232 words, rows at stride ROWW=68):
//   word hr*68+3        : LEFT halo (col c0-1) of row hr
//   words hr*68+4..+67  : main cols c0..c0+63   (16B-aligned: 272*hr+16)
//   word hr*68+68       : RIGHT halo (col c0+64) — lands in next row's free
//                         words +0..+2, no collision.
// Window read per (ic,row): 1x ds_read_b128 (main quad, aligned) + UNIFORM
// l/r pair at q=rowbase+3+col4*4: l=q[0], r=q[5] -> single ds_read2_b32
// (offset0:0 offset1:5). 2 DS ops/window (was 3), no col4==0 special case.
// LDS = 4*1232*4 = 19,712 B -> 8 blocks/CU (32 waves = HW max).
//
// Staging: depth-2 software pipeline (load quad j+2, then transform+write
// quad j) with named registers — <=3 float4 live, fits the 64-VGPR cap of
// __launch_bounds__(256,8) without spills while keeping 2 wave-loads in
// flight (128 concurrent 16B requests per wave).
// ---------------------------------------------------------------------------
#define TR 16
#define TC 64
#define HR 18
#define ROWW 68
#define ICW 1232

struct W6 { float l, m0, m1, m2, m3, r; };

__global__ __launch_bounds__(256, 8) void conv_kernel(const float* __restrict__ scores,
                                                      const float* __restrict__ tau,
                                                      const float* __restrict__ weight,
                                                      const float* __restrict__ bias,
                                                      float* __restrict__ out) {
    const int c0 = blockIdx.x * TC;
    const int r0 = blockIdx.y * TR;
    const int g  = blockIdx.z;
    const int t  = threadIdx.x;

    // Fully-dead tile: vectorized zero-fill, no loads.
    if (c0 > r0 + TR - 1) {
        const float4 z4 = make_float4(0.f, 0.f, 0.f, 0.f);
#pragma unroll
        for (int jj = 0; jj < 4; ++jj) {
            int idx = t + (jj << 8);              // 0..1023
            int c4  = idx & 15;
            int r   = (idx >> 4) & 15;
            int o   = idx >> 8;
            float4* p = (float4*)(out + (((size_t)((g << 2) + o) * L + (r0 + r)) * L + c0)) + c4;
            *p = z4;
        }
        return;
    }

    __shared__ __align__(16) float P[4][ICW];

    const bool interior = (c0 >= 1) && (c0 + TC + 1 <= r0) && (r0 + TR <= L - 1);

    const float* sbase = scores + (size_t)(g << 2) * L * L;
    const float* tbase = tau + (g << 2) * L;

    // quad decode: idx -> hr = idx>>6, ic = (idx>>4)&3, c4 = idx&15
    // quads 0..1151; jj=0..3 always valid, jj=4 valid iff t<128.
#define QDECODE(idx, hr, ic, c4, r) \
    int hr = (idx) >> 6; int ic = ((idx) >> 4) & 3; int c4 = (idx) & 15; int r = r0 - 1 + hr;

    if (interior) {
        float4 z0, z1, z2; float tv0, tv1, tv2;
        // ---- prologue: issue loads for quads jj=0,1 + halo loads ----
        {
            QDECODE(t, hr, ic, c4, r)
            z0  = *((const float4*)(sbase + (size_t)ic * L * L + (size_t)r * L + c0) + c4);
            tv0 = tbase[ic * L + r];
        }
        {
            QDECODE(t + 256, hr, ic, c4, r)
            z1  = *((const float4*)(sbase + (size_t)ic * L * L + (size_t)r * L + c0) + c4);
            tv1 = tbase[ic * L + r];
        }
        float hs = 0.f, ht = 0.f;
        int hoff = 0;
        if (t < 144) {
            int side = t & 1, j = t >> 1;
            int hic = j / HR, hhr = j - hic * HR;
            int r = r0 - 1 + hhr;
            int c = side ? (c0 + TC) : (c0 - 1);
            hs = sbase[(size_t)hic * L * L + (size_t)r * L + c];
            ht = tbase[hic * L + r];
            hoff = hic * ICW + hhr * ROWW + (side ? ROWW : 3);
        }
        float* Pf = &P[0][0];

        // ---- steady state: load jj+2, write jj ----
        {   // load jj=2
            QDECODE(t + 512, hr, ic, c4, r)
            z2  = *((const float4*)(sbase + (size_t)ic * L * L + (size_t)r * L + c0) + c4);
            tv2 = tbase[ic * L + r];
        }
        {   // write jj=0
            QDECODE(t, hr, ic, c4, r)
            float4 val;
            val.x = fmaxf(z0.x - tv0, 0.f); val.y = fmaxf(z0.y - tv0, 0.f);
            val.z = fmaxf(z0.z - tv0, 0.f); val.w = fmaxf(z0.w - tv0, 0.f);
            *((float4*)&P[ic][hr * ROWW + 4 + (c4 << 2)]) = val;
        }
        {   // load jj=3 into z0 slot
            QDECODE(t + 768, hr, ic, c4, r)
            z0  = *((const float4*)(sbase + (size_t)ic * L * L + (size_t)r * L + c0) + c4);
            tv0 = tbase[ic * L + r];
        }
        {   // write jj=1
            QDECODE(t + 256, hr, ic, c4, r)
            float4 val;
            val.x = fmaxf(z1.x - tv1, 0.f); val.y = fmaxf(z1.y - tv1, 0.f);
            val.z = fmaxf(z1.z - tv1, 0.f); val.w = fmaxf(z1.w - tv1, 0.f);
            *((float4*)&P[ic][hr * ROWW + 4 + (c4 << 2)]) = val;
        }
        if (t < 128) {  // load jj=4 into z1 slot
            QDECODE(t + 1024, hr, ic, c4, r)
            z1  = *((const float4*)(sbase + (size_t)ic * L * L + (size_t)r * L + c0) + c4);
            tv1 = tbase[ic * L + r];
        }
        {   // write jj=2
            QDECODE(t + 512, hr, ic, c4, r)
            float4 val;
            val.x = fmaxf(z2.x - tv2, 0.f); val.y = fmaxf(z2.y - tv2, 0.f);
            val.z = fmaxf(z2.z - tv2, 0.f); val.w = fmaxf(z2.w - tv2, 0.f);
            *((float4*)&P[ic][hr * ROWW + 4 + (c4 << 2)]) = val;
        }
        {   // write jj=3
            QDECODE(t + 768, hr, ic, c4, r)
            float4 val;
            val.x = fmaxf(z0.x - tv0, 0.f); val.y = fmaxf(z0.y - tv0, 0.f);
            val.z = fmaxf(z0.z - tv0, 0.f); val.w = fmaxf(z0.w - tv0, 0.f);
            *((float4*)&P[ic][hr * ROWW + 4 + (c4 << 2)]) = val;
        }
        if (t < 144) Pf[hoff] = fmaxf(hs - ht, 0.f);
        if (t < 128) {  // write jj=4
            QDECODE(t + 1024, hr, ic, c4, r)
            float4 val;
            val.x = fmaxf(z1.x - tv1, 0.f); val.y = fmaxf(z1.y - tv1, 0.f);
            val.z = fmaxf(z1.z - tv1, 0.f); val.w = fmaxf(z1.w - tv1, 0.f);
            *((float4*)&P[ic][hr * ROWW + 4 + (c4 << 2)]) = val;
        }
    } else {
        // ---- checked staging (boundary / diagonal tiles) ----
#pragma unroll
        for (int jj = 0; jj < 5; ++jj) {
            int idx = t + (jj << 8);
            if (idx < 1152) {
                QDECODE(idx, hr, ic, c4, r)
                int cb2 = c0 + (c4 << 2);
                float4 val = make_float4(0.f, 0.f, 0.f, 0.f);
                if (r >= 0 && r < L && cb2 <= r) {
                    float tv = tbase[ic * L + r];
                    float4 z = *((const float4*)(sbase + (size_t)ic * L * L + (size_t)r * L) + (cb2 >> 2));
                    val.x = fmaxf(z.x - tv, 0.f);
                    val.y = (cb2 + 1 <= r) ? fmaxf(z.y - tv, 0.f) : 0.f;
                    val.z = (cb2 + 2 <= r) ? fmaxf(z.z - tv, 0.f) : 0.f;
                    val.w = (cb2 + 3 <= r) ? fmaxf(z.w - tv, 0.f) : 0.f;
                }
                *((float4*)&P[ic][hr * ROWW + 4 + (c4 << 2)]) = val;
            }
        }
        if (t < 144) {
            int side = t & 1, j = t >> 1;
            int hic = j / HR, hhr = j - hic * HR;
            int r = r0 - 1 + hhr;
            int c = side ? (c0 + TC) : (c0 - 1);
            float val = 0.f;
            if (r >= 0 && r < L && c >= 0 && c <= r) {
                val = fmaxf(sbase[(size_t)hic * L * L + (size_t)r * L + c]
                            - tbase[hic * L + r], 0.f);
            }
            P[hic][hhr * ROWW + (side ? ROWW : 3)] = val;
        }
    }
    __syncthreads();

    // ---- compute ----
    const int o    = __builtin_amdgcn_readfirstlane(t >> 6);
    const int lane = t & 63;
    const int col4 = lane & 15;
    const int rq   = lane >> 4;                    // row quad: 0..3
    const int hb   = rq << 2;                      // staged-row base for this lane
    const int go   = (g << 2) + o;
    const int cb   = c0 + (col4 << 2);

    float w[4][9];
#pragma unroll
    for (int ic = 0; ic < 4; ++ic)
#pragma unroll
        for (int k = 0; k < 9; ++k) w[ic][k] = weight[((go << 2) + ic) * 9 + k];
    const float bb = bias[go];

    auto ldwin = [&](int ic, int hr) -> W6 {
        const float* rp = &P[ic][hr * ROWW];
        float4 M = *(const float4*)(rp + 4 + (col4 << 2));
        const float* q = rp + 3 + (col4 << 2);      // l = q[0], r = q[5] -> ds_read2_b32
        float lv = q[0];
        float rv = q[5];
        W6 x; x.l = lv; x.m0 = M.x; x.m1 = M.y; x.m2 = M.z; x.m3 = M.w; x.r = rv;
        return x;
    };

    float4 acc[4];
#pragma unroll
    for (int rr = 0; rr < 4; ++rr) acc[rr] = make_float4(bb, bb, bb, bb);

#pragma unroll
    for (int ic = 0; ic < 4; ++ic) {
        W6 a = ldwin(ic, hb);
        W6 b = ldwin(ic, hb + 1);
#pragma unroll
        for (int rr = 0; rr < 4; ++rr) {
            W6 c = ldwin(ic, hb + rr + 2);
            const W6 rows[3] = { a, b, c };
#pragma unroll
            for (int dy = 0; dy < 3; ++dy) {
                const W6& q = rows[dy];
                const float w0 = w[ic][dy * 3 + 0];
                const float w1 = w[ic][dy * 3 + 1];
                const float w2 = w[ic][dy * 3 + 2];
                acc[rr].x = fmaf(q.l,  w0, fmaf(q.m0, w1, fmaf(q.m1, w2, acc[rr].x)));
                acc[rr].y = fmaf(q.m0, w0, fmaf(q.m1, w1, fmaf(q.m2, w2, acc[rr].y)));
                acc[rr].z = fmaf(q.m1, w0, fmaf(q.m2, w1, fmaf(q.m3, w2, acc[rr].z)));
                acc[rr].w = fmaf(q.m2, w0, fmaf(q.m3, w1, fmaf(q.r,  w2, acc[rr].w)));
            }
            a = b; b = c;
        }
    }

    float* outp = out + ((size_t)go * L + (r0 + hb)) * L + cb;
    if (interior) {
#pragma unroll
        for (int rr = 0; rr < 4; ++rr)
            *(float4*)(outp + (size_t)rr * L) = acc[rr];
    } else {
#pragma unroll
        for (int rr = 0; rr < 4; ++rr) {
            int r = r0 + hb + rr;
            float4 res;
            res.x = (cb     <= r) ? acc[rr].x : 0.f;
            res.y = (cb + 1 <= r) ? acc[rr].y : 0.f;
            res.z = (cb + 2 <= r) ? acc[rr].z : 0.f;
            res.w = (cb + 3 <= r) ? acc[rr].w : 0.f;
            *(float4*)(outp + (size_t)rr * L) = res;
        }
    }
}

extern "C" void kernel_launch(void* const* d_in, const int* in_sizes, int n_in,
                              void* d_out, int out_size, void* d_ws, size_t ws_size,
                              hipStream_t stream) {
    const float* scores = (const float*)d_in[0];
    const float* weight = (const float*)d_in[1];
    const float* bias   = (const float*)d_in[2];
    float* out = (float*)d_out;
    float* tau = (float*)d_ws;                 // 16*2048 floats = 128 KB

    tau_kernel<<<(CIN * L) / 4, 256, 0, stream>>>(scores, tau);

    dim3 gridB(L / TC, L / TR, GROUPS);
    conv_kernel<<<gridB, 256, 0, stream>>>(scores, tau, weight, bias, out);
}

// Round 4
// 514.843 us; speedup vs baseline: 1.3747x; 1.3747x over previous
//
#include <hip/hip_runtime.h>

#define L 2048
#define CIN 16
#define GROUPS 4
#define NEG_INF  -1000000000.0f
#define POS_THRESH -100000000.0f

// ---------------------------------------------------------------------------
// Kernel A: sparsemax tau, one wave per row, FIXED-COST exact algorithm.
// (unchanged — proven)
// ---------------------------------------------------------------------------
__global__ __launch_bounds__(256) void tau_kernel(const float* __restrict__ scores,
                                                  float* __restrict__ tau_out) {
    const int wid  = (blockIdx.x << 2) + (threadIdx.x >> 6);
    const int lane = threadIdx.x & 63;
    const int ws   = threadIdx.x >> 6;            // wave slot in block
    const int ch   = wid >> 11;
    const int row  = wid & 2047;
    const int n    = row + 1;
    const float* zrow = scores + ((size_t)ch * L + row) * L;

    float v[32];
    float m = NEG_INF;
#pragma unroll
    for (int j = 0; j < 8; ++j) {
        int c4 = lane + (j << 6);
        int c  = c4 << 2;
        float4 z = make_float4(NEG_INF, NEG_INF, NEG_INF, NEG_INF);
        if (c < n) z = *((const float4*)zrow + c4);
        v[4*j+0] = (c + 0 < n) ? z.x : NEG_INF;
        v[4*j+1] = (c + 1 < n) ? z.y : NEG_INF;
        v[4*j+2] = (c + 2 < n) ? z.z : NEG_INF;
        v[4*j+3] = (c + 3 < n) ? z.w : NEG_INF;
        m = fmaxf(m, fmaxf(fmaxf(v[4*j+0], v[4*j+1]), fmaxf(v[4*j+2], v[4*j+3])));
    }
#pragma unroll
    for (int d = 32; d; d >>= 1) m = fmaxf(m, __shfl_xor(m, d, 64));

    const float thr = m - 1.0f;

    // ---- compact candidates {v > thr} into per-wave LDS buffer ----
    __shared__ float buf[4][64];
    int base = 0;
#pragma unroll
    for (int j = 0; j < 32; ++j) {
        bool p = v[j] > thr;
        unsigned long long mask = __ballot(p);
        if (mask) {
            if (p) {
                int pos = __builtin_amdgcn_mbcnt_lo((unsigned)mask, 0);
                pos = __builtin_amdgcn_mbcnt_hi((unsigned)(mask >> 32), pos);
                pos += base;
                if (pos < 64) buf[ws][pos] = v[j];
            }
            base += __popcll(mask);
        }
    }
    __syncthreads();
    const int cnt = base;

    float tau;
    if (cnt <= 64) {
        float x = (lane < cnt) ? buf[ws][lane] : NEG_INF;
        // bitonic sort, descending across 64 lanes
#pragma unroll
        for (int k = 2; k <= 64; k <<= 1) {
#pragma unroll
            for (int j = k >> 1; j > 0; j >>= 1) {
                float p = __shfl_xor(x, j, 64);
                bool desc    = ((lane & k) == 0);
                bool earlier = ((lane & j) == 0);
                float mx = fmaxf(x, p), mn = fminf(x, p);
                x = (desc == earlier) ? mx : mn;
            }
        }
        // inclusive prefix sum
        float csum = x;
#pragma unroll
        for (int d = 1; d < 64; d <<= 1) {
            float y = __shfl_up(csum, d, 64);
            if (lane >= d) csum += y;
        }
        bool cond = (1.0f + (float)(lane + 1) * x > csum) && (x > POS_THRESH);
        unsigned long long cmask = __ballot(cond);
        int k = (int)__popcll(cmask);             // k >= 1 always (max elem qualifies)
        float ck = __shfl(csum, k - 1, 64);
        tau = (ck - 1.0f) / (float)k;
    } else {
        // Michelot fallback — correctness safety net only.
        tau = thr;
        int k_prev = -1;
        for (int it = 0; it < 64; ++it) {
            float S = 0.0f, Kf = 0.0f;
#pragma unroll
            for (int j = 0; j < 32; ++j)
                if (v[j] > tau) { S += v[j]; Kf += 1.0f; }
#pragma unroll
            for (int d = 32; d; d >>= 1) {
                S  += __shfl_xor(S,  d, 64);
                Kf += __shfl_xor(Kf, d, 64);
            }
            int K = (int)Kf;
            if (K == k_prev) break;
            tau = (S - 1.0f) / Kf;
            k_prev = K;
        }
    }
    if (lane == 0) tau_out[ch * L + row] = tau;
}

// ---------------------------------------------------------------------------
// Kernel B: grouped 3x3 conv over on-the-fly probs = max(score - tau, 0).
// EXACT round-2 structure (the 496us/conv~131us version): TC=64 tile,
// loop-based issue-all-then-write staging, LDS P[4][18][68] with halos at
// [64] (right) / [67] (left), __launch_bounds__(256,8) -> 8 blocks/CU.
//
// ONE change vs round 2: the window's left/right neighbor values now come
// from DPP lane shifts instead of two extra b64 LDS reads.
//   q.l (col cb-1) = left  lane's M.w  -> v_mov_b32_dpp row_shr:1
//   q.r (col cb+4) = right lane's M.x  -> v_mov_b32_dpp row_shl:1
// DPP rows are 16 lanes = exactly our col4 groups. Edge lanes (col4==0 for l,
// col4==15 for r) have no valid source lane; with bound_ctrl=0 they keep the
// 'old' operand, which we feed with the halo word fetched by ONE broadcast-
// friendly ds_read_b32 ([67] for col4<15, [64] for col4==15).
// DS ops per window: 3 -> 2 (b128 + b32); edge handling moves to the idle
// VALU pipe. Registers strictly fewer than round 2 -> no spill risk.
// ---------------------------------------------------------------------------
#define TR 16
#define TC 64
#define HR 18
#define PST 68

struct W6 { float l, m0, m1, m2, m3, r; };

__device__ __forceinline__ float dpp_shr1(float src, float old) {
    // lane i <- lane i-1 within each 16-lane row; invalid lanes keep 'old'
    return __builtin_bit_cast(float, __builtin_amdgcn_update_dpp(
        __builtin_bit_cast(int, old), __builtin_bit_cast(int, src),
        0x111, 0xF, 0xF, false));
}
__device__ __forceinline__ float dpp_shl1(float src, float old) {
    // lane i <- lane i+1 within each 16-lane row; invalid lanes keep 'old'
    return __builtin_bit_cast(float, __builtin_amdgcn_update_dpp(
        __builtin_bit_cast(int, old), __builtin_bit_cast(int, src),
        0x101, 0xF, 0xF, false));
}

__global__ __launch_bounds__(256, 8) void conv_kernel(const float* __restrict__ scores,
                                                      const float* __restrict__ tau,
                                                      const float* __restrict__ weight,
                                                      const float* __restrict__ bias,
                                                      float* __restrict__ out) {
    const int c0 = blockIdx.x * TC;
    const int r0 = blockIdx.y * TR;
    const int g  = blockIdx.z;
    const int t  = threadIdx.x;

    // Fully-dead tile: vectorized zero-fill, no loads.
    if (c0 > r0 + TR - 1) {
        const float4 z4 = make_float4(0.f, 0.f, 0.f, 0.f);
#pragma unroll
        for (int jj = 0; jj < 4; ++jj) {
            int idx = t + (jj << 8);              // 0..1023
            int c4  = idx & 15;
            int r   = (idx >> 4) & 15;
            int o   = idx >> 8;
            float4* p = (float4*)(out + (((size_t)((g << 2) + o) * L + (r0 + r)) * L + c0)) + c4;
            *p = z4;
        }
        return;
    }

    __shared__ __align__(16) float P[4][HR][PST];

    const bool interior = (c0 >= 1) && (c0 + TC + 1 <= r0) && (r0 + TR <= L - 1);

    const float* sbase = scores + (size_t)(g << 2) * L * L;
    const float* tbase = tau + (g << 2) * L;

    // main quads: 4 ic x 18 hr x 16 c4 = 1152, flat layout [hr][ic][c4]
    float4 zr[5];
    float  tvr[5];

    if (interior) {
        // ---- issue ALL global loads first ----
#pragma unroll
        for (int jj = 0; jj < 5; ++jj) {
            int idx = t + (jj << 8);
            if (idx < 1152) {
                int hr = idx >> 6, ic = (idx >> 4) & 3, c4 = idx & 15;
                int r  = r0 - 1 + hr;
                zr[jj]  = *((const float4*)(sbase + (size_t)ic * L * L + (size_t)r * L + c0) + c4);
                tvr[jj] = tbase[ic * L + r];
            }
        }
        float hv = 0.f;
        int hic = 0, hhr = 0, hside = 0;
        if (t < 144) {
            hside = t & 1;
            int j = t >> 1;
            hic = j / HR; hhr = j - hic * HR;
            int r = r0 - 1 + hhr;
            int c = hside ? (c0 + TC) : (c0 - 1);
            hv = fmaxf(sbase[(size_t)hic * L * L + (size_t)r * L + c] - tbase[hic * L + r], 0.f);
        }
        // ---- transform + LDS writes ----
#pragma unroll
        for (int jj = 0; jj < 5; ++jj) {
            int idx = t + (jj << 8);
            if (idx < 1152) {
                int hr = idx >> 6, ic = (idx >> 4) & 3, c4 = idx & 15;
                float tv = tvr[jj];
                float4 z = zr[jj];
                float4 val;
                val.x = fmaxf(z.x - tv, 0.f);
                val.y = fmaxf(z.y - tv, 0.f);
                val.z = fmaxf(z.z - tv, 0.f);
                val.w = fmaxf(z.w - tv, 0.f);
                *((float4*)&P[ic][hr][c4 << 2]) = val;
            }
        }
        if (t < 144) P[hic][hhr][hside ? TC : 67] = hv;
    } else {
        // ---- checked staging (boundary / diagonal tiles) ----
#pragma unroll
        for (int jj = 0; jj < 5; ++jj) {
            int idx = t + (jj << 8);
            zr[jj] = make_float4(0.f, 0.f, 0.f, 0.f);
            tvr[jj] = 0.f;
            if (idx < 1152) {
                int hr = idx >> 6, ic = (idx >> 4) & 3, c4 = idx & 15;
                int r  = r0 - 1 + hr;
                int cb = c0 + (c4 << 2);
                if (r >= 0 && r < L && cb <= r) {
                    zr[jj]  = *((const float4*)(sbase + (size_t)ic * L * L + (size_t)r * L) + (cb >> 2));
                    tvr[jj] = tbase[ic * L + r];
                }
            }
        }
        float hv = 0.f;
        int hic = 0, hhr = 0, hside = 0;
        if (t < 144) {
            hside = t & 1;
            int j = t >> 1;
            hic = j / HR; hhr = j - hic * HR;
            int r = r0 - 1 + hhr;
            int c = hside ? (c0 + TC) : (c0 - 1);
            if (r >= 0 && r < L && c >= 0 && c <= r)
                hv = fmaxf(sbase[(size_t)hic * L * L + (size_t)r * L + c] - tbase[hic * L + r], 0.f);
        }
#pragma unroll
        for (int jj = 0; jj < 5; ++jj) {
            int idx = t + (jj << 8);
            if (idx < 1152) {
                int hr = idx >> 6, ic = (idx >> 4) & 3, c4 = idx & 15;
                int r  = r0 - 1 + hr;
                int cb = c0 + (c4 << 2);
                float tv = tvr[jj];
                float4 z = zr[jj];
                float4 val = make_float4(0.f, 0.f, 0.f, 0.f);
                if (r >= 0 && r < L && cb <= r) {
                    val.x = fmaxf(z.x - tv, 0.f);
                    val.y = (cb + 1 <= r) ? fmaxf(z.y - tv, 0.f) : 0.f;
                    val.z = (cb + 2 <= r) ? fmaxf(z.z - tv, 0.f) : 0.f;
                    val.w = (cb + 3 <= r) ? fmaxf(z.w - tv, 0.f) : 0.f;
                }
                *((float4*)&P[ic][hr][c4 << 2]) = val;
            }
        }
        if (t < 144) P[hic][hhr][hside ? TC : 67] = hv;
    }
    __syncthreads();

    // ---- compute ----
    const int o    = __builtin_amdgcn_readfirstlane(t >> 6);
    const int lane = t & 63;
    const int col4 = lane & 15;
    const int rq   = lane >> 4;                    // row quad: 0..3
    const int hb   = rq << 2;                      // staged-row base for this lane
    const int go   = (g << 2) + o;
    const int cb   = c0 + (col4 << 2);
    const int hidx = (col4 == 15) ? 64 : 67;       // halo word this lane may need

    float w[4][9];
#pragma unroll
    for (int ic = 0; ic < 4; ++ic)
#pragma unroll
        for (int k = 0; k < 9; ++k) w[ic][k] = weight[((go << 2) + ic) * 9 + k];
    const float bb = bias[go];

    auto ldwin = [&](int ic, int hr) -> W6 {
        const float* rp = &P[ic][hr][0];
        float4 M = *(const float4*)(rp + (col4 << 2));
        float h  = rp[hidx];                       // broadcast-friendly b32
        W6 q;
        q.l  = dpp_shr1(M.w, h);                   // left lane's m3; col4==0 -> halo[67]
        q.r  = dpp_shl1(M.x, h);                   // right lane's m0; col4==15 -> halo[64]
        q.m0 = M.x; q.m1 = M.y; q.m2 = M.z; q.m3 = M.w;
        return q;
    };

    float4 acc[4];
#pragma unroll
    for (int rr = 0; rr < 4; ++rr) acc[rr] = make_float4(bb, bb, bb, bb);

#pragma unroll
    for (int ic = 0; ic < 4; ++ic) {
        W6 a = ldwin(ic, hb);
        W6 b = ldwin(ic, hb + 1);
#pragma unroll
        for (int rr = 0; rr < 4; ++rr) {
            W6 c = ldwin(ic, hb + rr + 2);
            const W6 rows[3] = { a, b, c };
#pragma unroll
            for (int dy = 0; dy < 3; ++dy) {
                const W6& q = rows[dy];
                const float w0 = w[ic][dy * 3 + 0];
                const float w1 = w[ic][dy * 3 + 1];
                const float w2 = w[ic][dy * 3 + 2];
                acc[rr].x = fmaf(q.l,  w0, fmaf(q.m0, w1, fmaf(q.m1, w2, acc[rr].x)));
                acc[rr].y = fmaf(q.m0, w0, fmaf(q.m1, w1, fmaf(q.m2, w2, acc[rr].y)));
                acc[rr].z = fmaf(q.m1, w0, fmaf(q.m2, w1, fmaf(q.m3, w2, acc[rr].z)));
                acc[rr].w = fmaf(q.m2, w0, fmaf(q.m3, w1, fmaf(q.r,  w2, acc[rr].w)));
            }
            a = b; b = c;
        }
    }

    float* outp = out + ((size_t)go * L + (r0 + hb)) * L + cb;
    if (interior) {
#pragma unroll
        for (int rr = 0; rr < 4; ++rr)
            *(float4*)(outp + (size_t)rr * L) = acc[rr];
    } else {
#pragma unroll
        for (int rr = 0; rr < 4; ++rr) {
            int r = r0 + hb + rr;
            float4 res;
            res.x = (cb     <= r) ? acc[rr].x : 0.f;
            res.y = (cb + 1 <= r) ? acc[rr].y : 0.f;
            res.z = (cb + 2 <= r) ? acc[rr].z : 0.f;
            res.w = (cb + 3 <= r) ? acc[rr].w : 0.f;
            *(float4*)(outp + (size_t)rr * L) = res;
        }
    }
}

extern "C" void kernel_launch(void* const* d_in, const int* in_sizes, int n_in,
                              void* d_out, int out_size, void* d_ws, size_t ws_size,
                              hipStream_t stream) {
    const float* scores = (const float*)d_in[0];
    const float* weight = (const float*)d_in[1];
    const float* bias   = (const float*)d_in[2];
    float* out = (float*)d_out;
    float* tau = (float*)d_ws;                 // 16*2048 floats = 128 KB

    tau_kernel<<<(CIN * L) / 4, 256, 0, stream>>>(scores, tau);

    dim3 gridB(L / TC, L / TR, GROUPS);
    conv_kernel<<<gridB, 256, 0, stream>>>(scores, tau, weight, bias, out);
}